// Round 5
// baseline (41570.157 us; speedup 1.0000x reference)
//
#include <hip/hip_runtime.h>

// Problem constants (reference: B,T,V,E,H = 16,64,32000,256,1024)
#define B_ 16
#define T_ 64
#define V_ 32000
#define E_ 256
#define H_ 1024
#define G4_ (4 * H_)      // 4096 gate width
#define KE_ (E_ + H_)     // 1280 encoder GEMM K
#define KD_ (E_ + 2*H_)   // 2304 decoder GEMM K

typedef unsigned short ushort_t;
typedef unsigned int uint_t;
typedef __attribute__((ext_vector_type(8))) short short8;
typedef __attribute__((ext_vector_type(4))) float float4v;

__device__ __forceinline__ float b2f(ushort_t u) {
    return __uint_as_float(((uint_t)u) << 16);
}
__device__ __forceinline__ ushort_t f2b(float f) {
    uint_t u = __float_as_uint(f);
    u = (u + 0x7fffu + ((u >> 16) & 1u)) >> 16;   // round-to-nearest-even
    return (ushort_t)u;
}
__device__ __forceinline__ float sigf(float x) {
    return 1.f / (1.f + expf(-x));
}

// ---------------------------------------------------------------------------
// Cost model measured on THIS harness (r0-r3): kernel launch gap ~22-26us;
// 512-block grid barrier ~30us (release-RMW serialization: 512 x ~60ns).
// => minimize DISPATCHES, and use FEW-BLOCK persistent kernels whose barrier
// cost scales with block count (64 blocks -> ~8us predicted).
// Protocol (verified correct in r2): arrive = syncthreads + one agent-scope
// release-RMW per block; wait = RELAXED spin + ONE acquire fence.
// Deadlock-safe: 64 blocks, 256 thr -> trivially co-resident on 256 CUs.
// ---------------------------------------------------------------------------
__device__ __forceinline__ void grid_barrier(int* cnt, int target) {
    __syncthreads();
    if (threadIdx.x == 0) {
        __hip_atomic_fetch_add(cnt, 1, __ATOMIC_RELEASE, __HIP_MEMORY_SCOPE_AGENT);
        while (__hip_atomic_load(cnt, __ATOMIC_RELAXED, __HIP_MEMORY_SCOPE_AGENT) < target)
            __builtin_amdgcn_s_sleep(8);
        __builtin_amdgcn_fence(__ATOMIC_ACQUIRE, "agent");   // one inv, not per-poll
    }
    __syncthreads();
}

// ---------------------------------------------------------------------------
// Zero-init fp32 state (hbuf x2, cbuf, attn, ctx = 5*16384) + 512 counters.
// ---------------------------------------------------------------------------
__global__ __launch_bounds__(256) void init_kernel(float* __restrict__ state,
                                                   int* __restrict__ cnts, int n)
{
    const int i = blockIdx.x * 256 + threadIdx.x;
    if (i < n) state[i] = 0.f;
    if (i < 512) cnts[i] = 0;
}

// ---------------------------------------------------------------------------
// Persistent encoder: ONE kernel runs all 64 LSTM steps. 64 blocks; block
// owns hu-slice [bid*16, bid*16+16) across all 4 gates (64 cols). Threads =
// 4 k-slices x 64 cols. Gates via LDS exchange; c lives in LDS for the whole
// kernel (written to cbuf at the end for the decoder). 1 grid barrier/step.
// ---------------------------------------------------------------------------
__global__ __launch_bounds__(256, 1) void enc_persist_kernel(
    const float* __restrict__ emb, const int* __restrict__ enc_in,
    const float* __restrict__ Wk, const float* __restrict__ bias,
    const int* __restrict__ enc_len, float* __restrict__ hbuf,
    float* __restrict__ cbuf, float* __restrict__ memory,
    int* __restrict__ cnts)
{
    const int bid = blockIdx.x, tid = threadIdx.x;
    const int hu0 = bid * 16;
    const int slice = tid >> 6, colIdx = tid & 63;
    const int g_ = colIdx >> 4, j_ = colIdx & 15;
    const int col = g_ * 1024 + hu0 + j_;
    const int k0 = slice * (KE_ / 4);            // 320 k per slice

    __shared__ float zs[4][4][16][17];           // [slice][g][j][b] (+pad)
    __shared__ float cs[16][16];                 // [b][j]

    const int bg = tid >> 4, jg = tid & 15;      // gates mapping
    cs[bg][jg] = 0.f;
    const int my_len = enc_len[bg];
    __syncthreads();

    for (int t = 0; t < T_; ++t) {
        const float* h_prev = hbuf + (t & 1) * (B_ * H_);
        float*       h_next = hbuf + ((t + 1) & 1) * (B_ * H_);

        int vidx[16];
        #pragma unroll
        for (int b = 0; b < 16; ++b) vidx[b] = enc_in[b * T_ + t];

        float acc[16];
        #pragma unroll
        for (int b = 0; b < 16; ++b) acc[b] = 0.f;

        for (int g = 0; g < KE_ / 16; ++g) {     // 80 groups of 4 k
            const int k = k0 + g * 4;
            const float* wp = Wk + (size_t)k * G4_ + col;
            const float w0 = wp[0];
            const float w1 = wp[G4_];
            const float w2 = wp[2 * G4_];
            const float w3 = wp[3 * G4_];
            if (k < E_) {                        // boundaries are x4 aligned
                #pragma unroll
                for (int b = 0; b < 16; ++b) {
                    const float4 xv = *(const float4*)(emb + (size_t)vidx[b] * E_ + k);
                    acc[b] = fmaf(xv.x, w0, acc[b]);
                    acc[b] = fmaf(xv.y, w1, acc[b]);
                    acc[b] = fmaf(xv.z, w2, acc[b]);
                    acc[b] = fmaf(xv.w, w3, acc[b]);
                }
            } else {
                const float* hp = h_prev + (k - E_);
                #pragma unroll
                for (int b = 0; b < 16; ++b) {
                    const float4 xv = *(const float4*)(hp + b * H_);
                    acc[b] = fmaf(xv.x, w0, acc[b]);
                    acc[b] = fmaf(xv.y, w1, acc[b]);
                    acc[b] = fmaf(xv.z, w2, acc[b]);
                    acc[b] = fmaf(xv.w, w3, acc[b]);
                }
            }
        }
        #pragma unroll
        for (int b = 0; b < 16; ++b) zs[slice][g_][j_][b] = acc[b];
        __syncthreads();

        // ---- gates: thread (bg, jg) handles one (b, hu) element ----
        {
            float z[4];
            #pragma unroll
            for (int g = 0; g < 4; ++g)
                z[g] = bias[g * H_ + hu0 + jg]
                     + ((zs[0][g][jg][bg] + zs[1][g][jg][bg])
                     +  (zs[2][g][jg][bg] + zs[3][g][jg][bg]));
            const float cold = cs[bg][jg];
            const float cn = cold * sigf(z[2] + 1.f) + sigf(z[0]) * tanhf(z[1]);
            const float hn = tanhf(cn) * sigf(z[3]);
            const bool valid = t < my_len;
            cs[bg][jg] = valid ? cn : cold;
            const int hcol = hu0 + jg;
            h_next[bg * H_ + hcol] = valid ? hn : h_prev[bg * H_ + hcol];
            memory[((size_t)bg * T_ + t) * H_ + hcol] = valid ? hn : 0.f;
        }
        if (t < T_ - 1) grid_barrier(cnts + t, 64);
    }
    cbuf[bg * H_ + hu0 + jg] = cs[bg][jg];       // final c for the decoder
}

// ---------------------------------------------------------------------------
// keys = memory[1024,1024] @ Wm. Grid 256 = (64 rowtile, 4 cc), float4 k.
// ---------------------------------------------------------------------------
__global__ __launch_bounds__(256) void keys_gemm_kernel(
    const float* __restrict__ memory, const float* __restrict__ Wm,
    float* __restrict__ keys)
{
    const int rt = blockIdx.x >> 2;
    const int cc = blockIdx.x & 3;
    const int col = cc * 256 + threadIdx.x;
    float acc[16];
    #pragma unroll
    for (int m = 0; m < 16; ++m) acc[m] = 0.f;
    for (int g = 0; g < H_ / 4; ++g) {
        const int k = g * 4;
        const float* wp = Wm + (size_t)k * H_ + col;
        const float w0 = wp[0], w1 = wp[H_], w2 = wp[2 * H_], w3 = wp[3 * H_];
        const float* mp = memory + (size_t)(rt * 16) * H_ + k;
        #pragma unroll
        for (int m = 0; m < 16; ++m) {
            const float4 xv = *(const float4*)(mp + (size_t)m * H_);
            acc[m] = fmaf(xv.x, w0, acc[m]);
            acc[m] = fmaf(xv.y, w1, acc[m]);
            acc[m] = fmaf(xv.z, w2, acc[m]);
            acc[m] = fmaf(xv.w, w3, acc[m]);
        }
    }
    #pragma unroll
    for (int m = 0; m < 16; ++m)
        keys[(size_t)(rt * 16 + m) * H_ + col] = acc[m];
}

// ---------------------------------------------------------------------------
// Persistent decoder: ONE kernel, 64 blocks, 4 phases + 4 barriers per step.
//  ph1: LSTM (full-K per block, gates in LDS, c LDS-resident)
//  ph2: q partials (blocks 0..15, k-split 4 x colchunk 4)
//  ph3: per-batch q-reduce + scores + softmax + context (blocks 0..15)
//  ph4: attn2 (full-K, block owns 16 cols) + attn/dec_out write
// ---------------------------------------------------------------------------
__global__ __launch_bounds__(256, 1) void dec_persist_kernel(
    const float* __restrict__ emb, const int* __restrict__ dec_in,
    const float* __restrict__ Wk, const float* __restrict__ bias,
    const float* __restrict__ Wq, const float* __restrict__ v_att,
    const float* __restrict__ attnK, const int* __restrict__ enc_len,
    const int* __restrict__ dec_len, const float* __restrict__ keys,
    const float* __restrict__ memory, float* __restrict__ hbuf,
    const float* __restrict__ cbuf, float* __restrict__ attnbuf,
    float* __restrict__ ctxbuf, float* __restrict__ qpart,
    float* __restrict__ dec_out, int* __restrict__ cnts)
{
    const int bid = blockIdx.x, tid = threadIdx.x;
    const int hu0 = bid * 16;
    const int slice = tid >> 6, colIdx = tid & 63;
    const int g_ = colIdx >> 4, j_ = colIdx & 15;
    const int col1 = g_ * 1024 + hu0 + j_;
    const int k01 = slice * (KD_ / 4);           // 576 k per slice

    __shared__ float zs[4][4][16][17];
    __shared__ float cs[16][16];
    __shared__ float qloc[1024];
    __shared__ float sc[T_];
    __shared__ float al[T_];
    __shared__ float aps[16][16][17];            // [ks][ci][b] (+pad)

    const int bg = tid >> 4, jg = tid & 15;
    cs[bg][jg] = cbuf[bg * H_ + hu0 + jg];       // c0 = encoder final c
    const int my_dlen = dec_len[bg];
    __syncthreads();

    for (int t = 0; t < T_; ++t) {
        const float* h_prev = hbuf + (t & 1) * (B_ * H_);
        float*       h2     = hbuf + ((t + 1) & 1) * (B_ * H_);

        // ================= phase 1: LSTM =================
        {
            int vidx[16];
            #pragma unroll
            for (int b = 0; b < 16; ++b) vidx[b] = dec_in[b * T_ + t];

            float acc[16];
            #pragma unroll
            for (int b = 0; b < 16; ++b) acc[b] = 0.f;

            for (int g = 0; g < KD_ / 16; ++g) { // 144 groups of 4 k
                const int k = k01 + g * 4;
                const float* wp = Wk + (size_t)k * G4_ + col1;
                const float w0 = wp[0];
                const float w1 = wp[G4_];
                const float w2 = wp[2 * G4_];
                const float w3 = wp[3 * G4_];
                if (k < E_) {
                    #pragma unroll
                    for (int b = 0; b < 16; ++b) {
                        const float4 xv = *(const float4*)(emb + (size_t)vidx[b] * E_ + k);
                        acc[b] = fmaf(xv.x, w0, acc[b]);
                        acc[b] = fmaf(xv.y, w1, acc[b]);
                        acc[b] = fmaf(xv.z, w2, acc[b]);
                        acc[b] = fmaf(xv.w, w3, acc[b]);
                    }
                } else {
                    const float* xb = (k < E_ + H_) ? (attnbuf + (k - E_))
                                                    : (h_prev + (k - E_ - H_));
                    #pragma unroll
                    for (int b = 0; b < 16; ++b) {
                        const float4 xv = *(const float4*)(xb + b * H_);
                        acc[b] = fmaf(xv.x, w0, acc[b]);
                        acc[b] = fmaf(xv.y, w1, acc[b]);
                        acc[b] = fmaf(xv.z, w2, acc[b]);
                        acc[b] = fmaf(xv.w, w3, acc[b]);
                    }
                }
            }
            #pragma unroll
            for (int b = 0; b < 16; ++b) zs[slice][g_][j_][b] = acc[b];
            __syncthreads();
            float z[4];
            #pragma unroll
            for (int g = 0; g < 4; ++g)
                z[g] = bias[g * H_ + hu0 + jg]
                     + ((zs[0][g][jg][bg] + zs[1][g][jg][bg])
                     +  (zs[2][g][jg][bg] + zs[3][g][jg][bg]));
            const float cold = cs[bg][jg];
            const float cn = cold * sigf(z[2] + 1.f) + sigf(z[0]) * tanhf(z[1]);
            const float hn = tanhf(cn) * sigf(z[3]);
            cs[bg][jg] = cn;
            h2[bg * H_ + hu0 + jg] = hn;
        }
        grid_barrier(cnts + 64 + t * 4 + 0, 64);

        // ================= phase 2: q partials (blocks 0..15) =================
        if (bid < 16) {
            const int ks = bid >> 2, cc = bid & 3;
            const int colq = cc * 256 + tid;
            float qa[16];
            #pragma unroll
            for (int b = 0; b < 16; ++b) qa[b] = 0.f;
            for (int g = 0; g < 64; ++g) {
                const int k = ks * 256 + g * 4;
                const float* wp = Wq + (size_t)k * H_ + colq;
                const float w0 = wp[0], w1 = wp[H_], w2 = wp[2 * H_], w3 = wp[3 * H_];
                #pragma unroll
                for (int b = 0; b < 16; ++b) {
                    const float4 xv = *(const float4*)(h2 + b * H_ + k);
                    qa[b] = fmaf(xv.x, w0, qa[b]);
                    qa[b] = fmaf(xv.y, w1, qa[b]);
                    qa[b] = fmaf(xv.z, w2, qa[b]);
                    qa[b] = fmaf(xv.w, w3, qa[b]);
                }
            }
            #pragma unroll
            for (int b = 0; b < 16; ++b)
                qpart[(size_t)(ks * 16 + b) * H_ + colq] = qa[b];
        }
        grid_barrier(cnts + 64 + t * 4 + 1, 64);

        // ===== phase 3: q-reduce + scores + softmax + context (blocks 0..15) =====
        if (bid < 16) {
            const int b = bid;
            {   // reduce 4 k-split q partials into LDS
                const int c0 = tid * 4;
                const float4 s0 = *(const float4*)(qpart + (size_t)(0 * 16 + b) * H_ + c0);
                const float4 s1 = *(const float4*)(qpart + (size_t)(1 * 16 + b) * H_ + c0);
                const float4 s2 = *(const float4*)(qpart + (size_t)(2 * 16 + b) * H_ + c0);
                const float4 s3 = *(const float4*)(qpart + (size_t)(3 * 16 + b) * H_ + c0);
                qloc[c0 + 0] = (s0.x + s1.x) + (s2.x + s3.x);
                qloc[c0 + 1] = (s0.y + s1.y) + (s2.y + s3.y);
                qloc[c0 + 2] = (s0.z + s1.z) + (s2.z + s3.z);
                qloc[c0 + 3] = (s0.w + s1.w) + (s2.w + s3.w);
            }
            __syncthreads();
            const int wv = tid >> 6, lane = tid & 63;
            for (int tt = wv; tt < T_; tt += 4) {
                const float* kp = keys + ((size_t)b * T_ + tt) * H_;
                float s = 0.f;
                #pragma unroll
                for (int j = 0; j < 16; ++j) {
                    const int h = lane + j * 64;
                    s += tanhf(kp[h] + qloc[h]) * v_att[h];
                }
                #pragma unroll
                for (int off = 32; off; off >>= 1) s += __shfl_xor(s, off);
                if (lane == 0) sc[tt] = s;
            }
            __syncthreads();
            if (tid < 64) {
                const int len = enc_len[b];
                float s = (tid < len) ? sc[tid] : -1e9f;
                float m = s;
                #pragma unroll
                for (int off = 32; off; off >>= 1) m = fmaxf(m, __shfl_xor(m, off));
                const float e = expf(s - m);
                float sum = e;
                #pragma unroll
                for (int off = 32; off; off >>= 1) sum += __shfl_xor(sum, off);
                al[tid] = e / sum;
            }
            __syncthreads();
            #pragma unroll
            for (int i = 0; i < 4; ++i) {
                const int colc = tid + i * 256;
                const float* mp = memory + (size_t)b * T_ * H_ + colc;
                float a0 = 0.f, a1 = 0.f, a2 = 0.f, a3 = 0.f;
                #pragma unroll
                for (int t2 = 0; t2 < T_; t2 += 4) {
                    a0 = fmaf(al[t2 + 0], mp[(size_t)(t2 + 0) * H_], a0);
                    a1 = fmaf(al[t2 + 1], mp[(size_t)(t2 + 1) * H_], a1);
                    a2 = fmaf(al[t2 + 2], mp[(size_t)(t2 + 2) * H_], a2);
                    a3 = fmaf(al[t2 + 3], mp[(size_t)(t2 + 3) * H_], a3);
                }
                ctxbuf[b * H_ + colc] = (a0 + a1) + (a2 + a3);
            }
        }
        grid_barrier(cnts + 64 + t * 4 + 2, 64);

        // ================= phase 4: attn2 + finish =================
        {
            const int ks4 = tid >> 4, ci = tid & 15;
            const int col4 = hu0 + ci;
            float aa[16];
            #pragma unroll
            for (int b = 0; b < 16; ++b) aa[b] = 0.f;
            for (int g = 0; g < 32; ++g) {       // kper = 128, groups of 4
                const int k = ks4 * 128 + g * 4;
                const float* wp = attnK + (size_t)k * H_ + col4;
                const float w0 = wp[0], w1 = wp[H_], w2 = wp[2 * H_], w3 = wp[3 * H_];
                const float* xb = (k < H_) ? (h2 + k) : (ctxbuf + (k - H_));
                #pragma unroll
                for (int b = 0; b < 16; ++b) {
                    const float4 xv = *(const float4*)(xb + b * H_);
                    aa[b] = fmaf(xv.x, w0, aa[b]);
                    aa[b] = fmaf(xv.y, w1, aa[b]);
                    aa[b] = fmaf(xv.z, w2, aa[b]);
                    aa[b] = fmaf(xv.w, w3, aa[b]);
                }
            }
            #pragma unroll
            for (int b = 0; b < 16; ++b) aps[ks4][ci][b] = aa[b];
            __syncthreads();
            float s = 0.f;
            #pragma unroll
            for (int ks = 0; ks < 16; ks += 4)
                s += ((aps[ks + 0][jg][bg] + aps[ks + 1][jg][bg])
                   +  (aps[ks + 2][jg][bg] + aps[ks + 3][jg][bg]));
            attnbuf[bg * H_ + hu0 + jg] = s;
            dec_out[((size_t)bg * T_ + t) * H_ + hu0 + jg] = (t >= my_dlen) ? 0.f : s;
        }
        if (t < T_ - 1) grid_barrier(cnts + 64 + t * 4 + 3, 64);
    }
}

// ---------------------------------------------------------------------------
// Logits prep 1: split out_kernel fp32 [k][n] -> bf16 hi/lo TRANSPOSED [n][k].
// ---------------------------------------------------------------------------
__global__ __launch_bounds__(256) void bsplit_kernel(
    const float* __restrict__ Bw, ushort_t* __restrict__ Bh_t,
    ushort_t* __restrict__ Bl_t)
{
    __shared__ ushort_t Th[64][65];
    __shared__ ushort_t Tl[64][65];
    const int k0 = (blockIdx.x & 15) * 64;
    const int n0 = (blockIdx.x >> 4) * 64;
    const int tid = threadIdx.x;
    {
        const int nl = tid & 63, kb = tid >> 6;
        for (int i = 0; i < 16; ++i) {
            const int kl = kb + i * 4;
            const float f = Bw[(size_t)(k0 + kl) * V_ + n0 + nl];
            const ushort_t hi = f2b(f);
            Th[kl][nl] = hi;
            Tl[kl][nl] = f2b(f - b2f(hi));
        }
    }
    __syncthreads();
    {
        const int r = tid >> 2, c0 = (tid & 3) * 16;
        short8 vh0, vh1, vl0, vl1;
        #pragma unroll
        for (int j = 0; j < 8; ++j) {
            vh0[j] = (short)Th[c0 + j][r];
            vh1[j] = (short)Th[c0 + 8 + j][r];
            vl0[j] = (short)Tl[c0 + j][r];
            vl1[j] = (short)Tl[c0 + 8 + j][r];
        }
        ushort_t* ph = Bh_t + (size_t)(n0 + r) * 1024 + k0 + c0;
        ushort_t* pl = Bl_t + (size_t)(n0 + r) * 1024 + k0 + c0;
        *(short8*)ph = vh0;
        *(short8*)(ph + 8) = vh1;
        *(short8*)pl = vl0;
        *(short8*)(pl + 8) = vl1;
    }
}

// ---------------------------------------------------------------------------
// Logits prep 2: split dec_out fp32 [m][k] -> bf16 hi/lo [m][k]. Grid 512.
// ---------------------------------------------------------------------------
__global__ __launch_bounds__(256) void asplit_kernel(
    const float* __restrict__ A, ushort_t* __restrict__ Ah_g,
    ushort_t* __restrict__ Al_g)
{
    const size_t i0 = ((size_t)blockIdx.x * 256 + threadIdx.x) * 8;
    const float4 f0 = *(const float4*)(A + i0);
    const float4 f1 = *(const float4*)(A + i0 + 4);
    float f[8] = {f0.x, f0.y, f0.z, f0.w, f1.x, f1.y, f1.z, f1.w};
    short8 vh, vl;
    #pragma unroll
    for (int j = 0; j < 8; ++j) {
        const ushort_t hi = f2b(f[j]);
        vh[j] = (short)hi;
        vl[j] = (short)f2b(f[j] - b2f(hi));
    }
    *(short8*)(Ah_g + i0) = vh;
    *(short8*)(Al_g + i0) = vl;
}

// ---------------------------------------------------------------------------
// Logits from precomputed splits (direct global fragment loads + MFMA).
// ---------------------------------------------------------------------------
__global__ __launch_bounds__(256) void logits_pre_kernel(
    const ushort_t* __restrict__ Ah_g, const ushort_t* __restrict__ Al_g,
    const ushort_t* __restrict__ Bh_t, const ushort_t* __restrict__ Bl_t,
    float* __restrict__ out)
{
    const int tid = threadIdx.x;
    const int m0 = blockIdx.x * 128;
    const int n0 = blockIdx.y * 64;
    const int w = tid >> 6, lane = tid & 63;
    const int ml = lane & 15, quad = lane >> 4;

    float4v acc[2][4];
    #pragma unroll
    for (int ms = 0; ms < 2; ++ms)
        #pragma unroll
        for (int nn = 0; nn < 4; ++nn) acc[ms][nn] = (float4v){0.f, 0.f, 0.f, 0.f};

    const size_t arow0 = (size_t)(m0 + w * 32 + ml) * 1024;
    const size_t arow1 = (size_t)(m0 + w * 32 + 16 + ml) * 1024;

    for (int kb = 0; kb < 1024; kb += 32) {
        const int ko = kb + quad * 8;
        const short8 ah0 = *(const short8*)(Ah_g + arow0 + ko);
        const short8 al0 = *(const short8*)(Al_g + arow0 + ko);
        const short8 ah1 = *(const short8*)(Ah_g + arow1 + ko);
        const short8 al1 = *(const short8*)(Al_g + arow1 + ko);
        #pragma unroll
        for (int nn = 0; nn < 4; ++nn) {
            const size_t brow = (size_t)(n0 + nn * 16 + ml) * 1024 + ko;
            const short8 bfh = *(const short8*)(Bh_t + brow);
            const short8 bfl = *(const short8*)(Bl_t + brow);
            acc[0][nn] = __builtin_amdgcn_mfma_f32_16x16x32_bf16(ah0, bfh, acc[0][nn], 0, 0, 0);
            acc[0][nn] = __builtin_amdgcn_mfma_f32_16x16x32_bf16(ah0, bfl, acc[0][nn], 0, 0, 0);
            acc[0][nn] = __builtin_amdgcn_mfma_f32_16x16x32_bf16(al0, bfh, acc[0][nn], 0, 0, 0);
            acc[1][nn] = __builtin_amdgcn_mfma_f32_16x16x32_bf16(ah1, bfh, acc[1][nn], 0, 0, 0);
            acc[1][nn] = __builtin_amdgcn_mfma_f32_16x16x32_bf16(ah1, bfl, acc[1][nn], 0, 0, 0);
            acc[1][nn] = __builtin_amdgcn_mfma_f32_16x16x32_bf16(al1, bfh, acc[1][nn], 0, 0, 0);
        }
    }
    #pragma unroll
    for (int ms = 0; ms < 2; ++ms) {
        #pragma unroll
        for (int nn = 0; nn < 4; ++nn) {
            #pragma unroll
            for (int rg = 0; rg < 4; ++rg) {
                const int row = m0 + w * 32 + ms * 16 + quad * 4 + rg;
                const int colo = n0 + nn * 16 + ml;
                out[(size_t)row * V_ + colo] = acc[ms][nn][rg];
            }
        }
    }
}

// ---------------------------------------------------------------------------
// Fallback logits (in-kernel conversion, 64x64) — used if ws too small.
// ---------------------------------------------------------------------------
__global__ __launch_bounds__(256) void logits_kernel(
    const float* __restrict__ A, const float* __restrict__ Bw,
    float* __restrict__ out)
{
    __shared__ __align__(16) ushort_t Ah[64][44];
    __shared__ __align__(16) ushort_t Al[64][44];
    __shared__ __align__(16) ushort_t Bh[64][44];
    __shared__ __align__(16) ushort_t Bl[64][44];
    const int tid = threadIdx.x;
    const int m0 = blockIdx.x * 64;
    const int n0 = blockIdx.y * 64;
    const int wv = tid >> 6, lane = tid & 63;
    const int ml = lane & 15, quad = lane >> 4;

    float4v acc[4];
    #pragma unroll
    for (int nn = 0; nn < 4; ++nn) acc[nn] = (float4v){0.f, 0.f, 0.f, 0.f};

    for (int kb = 0; kb < 1024; kb += 32) {
        __syncthreads();
        {
            const int r = tid >> 2, c0 = (tid & 3) * 8;
            const float* ap = A + (size_t)(m0 + r) * 1024 + kb + c0;
            #pragma unroll
            for (int i = 0; i < 8; ++i) {
                const float f = ap[i];
                const ushort_t hi = f2b(f);
                Ah[r][c0 + i] = hi;
                Al[r][c0 + i] = f2b(f - b2f(hi));
            }
        }
        {
            const int cB = tid & 63, kq = tid >> 6;
            #pragma unroll
            for (int i = 0; i < 8; ++i) {
                const int k = kq * 8 + i;
                const float f = Bw[(size_t)(kb + k) * V_ + n0 + cB];
                const ushort_t hi = f2b(f);
                Bh[cB][k] = hi;
                Bl[cB][k] = f2b(f - b2f(hi));
            }
        }
        __syncthreads();
        const short8 afh = *(const short8*)&Ah[wv * 16 + ml][quad * 8];
        const short8 afl = *(const short8*)&Al[wv * 16 + ml][quad * 8];
        #pragma unroll
        for (int nn = 0; nn < 4; ++nn) {
            const short8 bfh = *(const short8*)&Bh[nn * 16 + ml][quad * 8];
            const short8 bfl = *(const short8*)&Bl[nn * 16 + ml][quad * 8];
            acc[nn] = __builtin_amdgcn_mfma_f32_16x16x32_bf16(afh, bfh, acc[nn], 0, 0, 0);
            acc[nn] = __builtin_amdgcn_mfma_f32_16x16x32_bf16(afh, bfl, acc[nn], 0, 0, 0);
            acc[nn] = __builtin_amdgcn_mfma_f32_16x16x32_bf16(afl, bfh, acc[nn], 0, 0, 0);
        }
    }
    #pragma unroll
    for (int nn = 0; nn < 4; ++nn) {
        #pragma unroll
        for (int rg = 0; rg < 4; ++rg) {
            const int row = m0 + wv * 16 + quad * 4 + rg;
            const int colo = n0 + nn * 16 + ml;
            out[(size_t)row * V_ + colo] = acc[nn][rg];
        }
    }
}

// ---------------------------------------------------------------------------
extern "C" void kernel_launch(void* const* d_in, const int* in_sizes, int n_in,
                              void* d_out, int out_size, void* d_ws, size_t ws_size,
                              hipStream_t stream) {
    (void)in_sizes; (void)n_in; (void)out_size;
    const int*   enc_in  = (const int*)d_in[0];
    const int*   dec_in  = (const int*)d_in[1];
    const int*   enc_len = (const int*)d_in[2];
    const int*   dec_len = (const int*)d_in[3];
    const float* emb     = (const float*)d_in[4];
    const float* encK    = (const float*)d_in[5];
    const float* encB    = (const float*)d_in[6];
    const float* decK    = (const float*)d_in[7];
    const float* decB    = (const float*)d_in[8];
    const float* Wm      = (const float*)d_in[9];
    const float* Wq      = (const float*)d_in[10];
    const float* v_att   = (const float*)d_in[11];
    const float* attnK   = (const float*)d_in[12];
    const float* outK    = (const float*)d_in[13];
    float* out = (float*)d_out;

    // Workspace layout (base ~13.2 MB; optional bf16 split +135 MB).
    float* hbuf    = (float*)d_ws;                       // 2 x [16,1024]
    float* cbuf    = hbuf + 2 * B_ * H_;                 // [16,1024]
    float* attnbuf = cbuf + B_ * H_;                     // [16,1024]
    float* ctxbuf  = attnbuf + B_ * H_;                  // [16,1024]
    float* qpart   = ctxbuf + B_ * H_;                   // 4 x [16,1024]
    int*   cnts    = (int*)(qpart + 4 * B_ * H_);        // 512 ints
    float* memory  = (float*)(cnts + 512);               // [16,64,1024]
    float* keys    = memory + (size_t)B_ * T_ * H_;      // [16,64,1024]
    float* dec_out = keys + (size_t)B_ * T_ * H_;        // [1024,1024]
    float* base_end = dec_out + (size_t)B_ * T_ * H_;

    ushort_t* Ah_g = (ushort_t*)base_end;                // [1024][1024] 2MB
    ushort_t* Al_g = Ah_g + (size_t)1024 * 1024;         // 2MB
    ushort_t* Bh_t = Al_g + (size_t)1024 * 1024;         // [32000][1024] 65.5MB
    ushort_t* Bl_t = Bh_t + (size_t)V_ * 1024;           // 65.5MB
    const size_t need = 148441088ull;
    const bool use_pre = ws_size >= need;

    // zero state (hbuf x2, cbuf, attnbuf, ctxbuf) + counters
    const int ninit = 5 * B_ * H_;
    init_kernel<<<(ninit + 255) / 256, 256, 0, stream>>>((float*)d_ws, cnts, ninit);

    if (use_pre)
        bsplit_kernel<<<16 * 500, 256, 0, stream>>>(outK, Bh_t, Bl_t);

    enc_persist_kernel<<<64, 256, 0, stream>>>(emb, enc_in, encK, encB, enc_len,
                                               hbuf, cbuf, memory, cnts);
    keys_gemm_kernel<<<256, 256, 0, stream>>>(memory, Wm, keys);
    dec_persist_kernel<<<64, 256, 0, stream>>>(emb, dec_in, decK, decB, Wq, v_att,
                                               attnK, enc_len, dec_len, keys, memory,
                                               hbuf, cbuf, attnbuf, ctxbuf, qpart,
                                               dec_out, cnts);

    if (use_pre) {
        asplit_kernel<<<512, 256, 0, stream>>>(dec_out, Ah_g, Al_g);
        logits_pre_kernel<<<dim3(8, 500), 256, 0, stream>>>(Ah_g, Al_g, Bh_t, Bl_t, out);
    } else {
        logits_kernel<<<dim3(16, 500), 256, 0, stream>>>(dec_out, outK, out);
    }
}

// Round 6
// 27756.317 us; speedup vs baseline: 1.4977x; 1.4977x over previous
//
#include <hip/hip_runtime.h>

// Problem constants (reference: B,T,V,E,H = 16,64,32000,256,1024)
#define B_ 16
#define T_ 64
#define V_ 32000
#define E_ 256
#define H_ 1024
#define G4_ (4 * H_)      // 4096 gate width
#define KE_ (E_ + H_)     // 1280 encoder GEMM K
#define KD_ (E_ + 2*H_)   // 2304 decoder GEMM K

typedef unsigned short ushort_t;
typedef unsigned int uint_t;
typedef __attribute__((ext_vector_type(8))) short short8;
typedef __attribute__((ext_vector_type(4))) float float4v;

__device__ __forceinline__ float b2f(ushort_t u) {
    return __uint_as_float(((uint_t)u) << 16);
}
__device__ __forceinline__ ushort_t f2b(float f) {
    uint_t u = __float_as_uint(f);
    u = (u + 0x7fffu + ((u >> 16) & 1u)) >> 16;   // round-to-nearest-even
    return (ushort_t)u;
}
__device__ __forceinline__ float sigf(float x) {
    return 1.f / (1.f + expf(-x));
}

// ---------------------------------------------------------------------------
// Cost model (r0-r5 measured):
//  - dispatch gap 5-22us (session-dependent) -> minimize dispatches (7 here).
//  - 64-block grids CANNOT stream weights: r5 dec_persist = 100 GB/s,
//    VALUBusy 1.8%, 35.8ms. Heavy phases need >=256 blocks.
//  - flat single-counter barriers serialize arrivals (~60ns x blocks).
// Hierarchical barrier: arrivals sharded over 16 lines (32 RMW each, in
// parallel); block 0 sweeps the 16 lines then bumps one flag line; all
// others spin RELAXED on the flag, then ONE acquire fence (r2/r5-verified
// protocol shape; no per-poll L2 invalidate).
// Counter layout per set: lines j at base+j*16 (j=0..15), flag at base+256.
// Targets are monotonic across the kernel's events: line=32*e, flag=e.
// Deadlock-safe: 512 blocks @ __launch_bounds__(256,2) -> 2 blocks/CU
// co-resident on 256 CUs (r2 precedent, passed twice).
// ---------------------------------------------------------------------------
__device__ __forceinline__ void gbar(int* base, int e) {
    __syncthreads();
    if (threadIdx.x == 0) {
        __hip_atomic_fetch_add(base + (blockIdx.x & 15) * 16, 1,
                               __ATOMIC_RELEASE, __HIP_MEMORY_SCOPE_AGENT);
        if (blockIdx.x == 0) {
            const int lt = 32 * e;
            for (int j = 0; j < 16; ++j) {
                while (__hip_atomic_load(base + j * 16, __ATOMIC_RELAXED,
                                         __HIP_MEMORY_SCOPE_AGENT) < lt)
                    __builtin_amdgcn_s_sleep(2);
            }
            __hip_atomic_fetch_add(base + 256, 1, __ATOMIC_RELEASE,
                                   __HIP_MEMORY_SCOPE_AGENT);
        } else {
            while (__hip_atomic_load(base + 256, __ATOMIC_RELAXED,
                                     __HIP_MEMORY_SCOPE_AGENT) < e)
                __builtin_amdgcn_s_sleep(8);
        }
        __builtin_amdgcn_fence(__ATOMIC_ACQUIRE, "agent");
    }
    __syncthreads();
}

// ---------------------------------------------------------------------------
// Zero-init fp32 state (hbuf x2, cbuf, attnbuf, ctxbuf = 81920 floats) and
// 1024 counter ints. Grid 320 x 256.
// ---------------------------------------------------------------------------
__global__ __launch_bounds__(256) void init_kernel(float* __restrict__ state,
                                                   int* __restrict__ cnts, int n)
{
    const int i = blockIdx.x * 256 + threadIdx.x;
    if (i < n) state[i] = 0.f;
    if (i < 1024) cnts[i] = 0;
}

// ---------------------------------------------------------------------------
// Persistent encoder: 512 blocks, whole 64-step loop. Per step:
//   [all 512] split-K GEMM (cc 0..15 x ks 0..31, K=40 each, float4)
//   bar -> [tail 64 blocks: ks>=28] gates (c in a register) -> bar.
// ---------------------------------------------------------------------------
__global__ __launch_bounds__(256, 2) void enc_persist_kernel(
    const float* __restrict__ emb, const int* __restrict__ enc_in,
    const float* __restrict__ Wk, const float* __restrict__ bias,
    const int* __restrict__ enc_len, float* __restrict__ hbuf,
    float* __restrict__ cbuf, float* __restrict__ memory,
    float* __restrict__ zpart, int* __restrict__ cnt)
{
    const int bid = blockIdx.x, tid = threadIdx.x;
    const int cc = bid & 15, ks = bid >> 4;
    const int col = cc * 256 + tid;
    const int k0 = ks * 40;
    const bool tail = ks >= 28;
    const int tb = (ks - 28) * 16 + cc;          // 0..63 when tail
    const int tidx = tb * 256 + tid;             // (b,hu) flat
    const int tb_b = tidx >> 10, tb_hu = tidx & 1023;
    float creg = 0.f;
    int my_len = 0;
    if (tail) my_len = enc_len[tb_b];

    int e = 0;
    for (int t = 0; t < T_; ++t) {
        const float* h_prev = hbuf + (t & 1) * (B_ * H_);
        float*       h_next = hbuf + ((t + 1) & 1) * (B_ * H_);

        int vidx[16];
        #pragma unroll
        for (int b = 0; b < 16; ++b) vidx[b] = enc_in[b * T_ + t];
        float acc[16];
        #pragma unroll
        for (int b = 0; b < 16; ++b) acc[b] = 0.f;

        for (int g = 0; g < 10; ++g) {           // 40 k in groups of 4
            const int k = k0 + g * 4;
            const float* wp = Wk + (size_t)k * G4_ + col;
            const float w0 = wp[0];
            const float w1 = wp[G4_];
            const float w2 = wp[2 * G4_];
            const float w3 = wp[3 * G4_];
            if (k < E_) {                        // boundaries x4-aligned
                #pragma unroll
                for (int b = 0; b < 16; ++b) {
                    const float4 xv = *(const float4*)(emb + (size_t)vidx[b] * E_ + k);
                    acc[b] = fmaf(xv.x, w0, acc[b]);
                    acc[b] = fmaf(xv.y, w1, acc[b]);
                    acc[b] = fmaf(xv.z, w2, acc[b]);
                    acc[b] = fmaf(xv.w, w3, acc[b]);
                }
            } else {
                const float* hp = h_prev + (k - E_);
                #pragma unroll
                for (int b = 0; b < 16; ++b) {
                    const float4 xv = *(const float4*)(hp + b * H_);
                    acc[b] = fmaf(xv.x, w0, acc[b]);
                    acc[b] = fmaf(xv.y, w1, acc[b]);
                    acc[b] = fmaf(xv.z, w2, acc[b]);
                    acc[b] = fmaf(xv.w, w3, acc[b]);
                }
            }
        }
        #pragma unroll
        for (int b = 0; b < 16; ++b)
            zpart[(size_t)(ks * 16 + b) * G4_ + col] = acc[b];

        gbar(cnt, ++e);

        if (tail) {
            float z[4];
            #pragma unroll
            for (int g = 0; g < 4; ++g) {
                float s0 = bias[g * H_ + tb_hu], s1 = 0.f, s2 = 0.f, s3 = 0.f;
                #pragma unroll
                for (int kss = 0; kss < 32; kss += 4) {
                    s0 += zpart[(size_t)((kss + 0) * 16 + tb_b) * G4_ + g * H_ + tb_hu];
                    s1 += zpart[(size_t)((kss + 1) * 16 + tb_b) * G4_ + g * H_ + tb_hu];
                    s2 += zpart[(size_t)((kss + 2) * 16 + tb_b) * G4_ + g * H_ + tb_hu];
                    s3 += zpart[(size_t)((kss + 3) * 16 + tb_b) * G4_ + g * H_ + tb_hu];
                }
                z[g] = (s0 + s1) + (s2 + s3);
            }
            const float cn = creg * sigf(z[2] + 1.f) + sigf(z[0]) * tanhf(z[1]);
            const float hn = tanhf(cn) * sigf(z[3]);
            const bool valid = t < my_len;
            creg = valid ? cn : creg;
            h_next[tb_b * H_ + tb_hu] = valid ? hn : h_prev[tb_b * H_ + tb_hu];
            memory[((size_t)tb_b * T_ + t) * H_ + tb_hu] = valid ? hn : 0.f;
        }
        if (t < T_ - 1) gbar(cnt, ++e);
    }
    if (tail) cbuf[tb_b * H_ + tb_hu] = creg;
}

// ---------------------------------------------------------------------------
// keys = memory[1024,1024] @ Wm. Grid 256 = (64 rowtile, 4 cc), float4 k.
// ---------------------------------------------------------------------------
__global__ __launch_bounds__(256) void keys_gemm_kernel(
    const float* __restrict__ memory, const float* __restrict__ Wm,
    float* __restrict__ keys)
{
    const int rt = blockIdx.x >> 2;
    const int cc = blockIdx.x & 3;
    const int col = cc * 256 + threadIdx.x;
    float acc[16];
    #pragma unroll
    for (int m = 0; m < 16; ++m) acc[m] = 0.f;
    for (int g = 0; g < H_ / 4; ++g) {
        const int k = g * 4;
        const float* wp = Wm + (size_t)k * H_ + col;
        const float w0 = wp[0], w1 = wp[H_], w2 = wp[2 * H_], w3 = wp[3 * H_];
        const float* mp = memory + (size_t)(rt * 16) * H_ + k;
        #pragma unroll
        for (int m = 0; m < 16; ++m) {
            const float4 xv = *(const float4*)(mp + (size_t)m * H_);
            acc[m] = fmaf(xv.x, w0, acc[m]);
            acc[m] = fmaf(xv.y, w1, acc[m]);
            acc[m] = fmaf(xv.z, w2, acc[m]);
            acc[m] = fmaf(xv.w, w3, acc[m]);
        }
    }
    #pragma unroll
    for (int m = 0; m < 16; ++m)
        keys[(size_t)(rt * 16 + m) * H_ + col] = acc[m];
}

// ---------------------------------------------------------------------------
// Persistent decoder: 512 blocks, whole 64-step loop. Per step, 5 phases:
//  P1 [512] split-K LSTM GEMM (K=2304)        -> bar
//  P2 [ 64] gates tail (c in register)        -> bar
//  P3 [128] q partials (32 ks x 4 cc, K=32)   -> bar
//  P4 [ 64] per-(b,cc): q-reduce + scores + softmax + ctx col-slice -> bar
//  P5 [ 64] attnout full-K via in-block 16-way split + finish -> bar
// All heavy streaming phases have >=128 blocks (r5 lesson).
// ---------------------------------------------------------------------------
__global__ __launch_bounds__(256, 2) void dec_persist_kernel(
    const float* __restrict__ emb, const int* __restrict__ dec_in,
    const float* __restrict__ Wk, const float* __restrict__ bias,
    const float* __restrict__ Wq, const float* __restrict__ v_att,
    const float* __restrict__ attnK, const int* __restrict__ enc_len,
    const int* __restrict__ dec_len, const float* __restrict__ keys,
    const float* __restrict__ memory, float* __restrict__ hbuf,
    const float* __restrict__ cbuf, float* __restrict__ attnbuf,
    float* __restrict__ ctxbuf, float* __restrict__ qpart,
    float* __restrict__ zpart, float* __restrict__ dec_out,
    int* __restrict__ cnt)
{
    const int bid = blockIdx.x, tid = threadIdx.x;
    const int cc = bid & 15, ks = bid >> 4;
    const int col = cc * 256 + tid;
    const int k0 = ks * 72;
    const bool tail = ks >= 28;
    const int tb = (ks - 28) * 16 + cc;
    const int tidx = tb * 256 + tid;
    const int tb_b = tidx >> 10, tb_hu = tidx & 1023;
    float creg = 0.f;
    if (tail) creg = cbuf[tb_b * H_ + tb_hu];    // c0 = encoder final c

    // P5 mapping (blocks 0..63): block owns cols [bid*16, bid*16+16), all b.
    const int p5_hu0 = bid * 16;
    const int p5_ks = tid >> 4, p5_ci = tid & 15;    // 16 ksplits x 16 cols
    const int p5_bg = tid >> 4, p5_jg = tid & 15;    // reduce mapping (b, j)
    int my_dl = 0;
    if (bid < 64) my_dl = dec_len[p5_bg];

    __shared__ float qloc[1024];
    __shared__ float sc[T_];
    __shared__ float al[T_];
    __shared__ float aps[16][16][17];

    int e = 0;
    for (int t = 0; t < T_; ++t) {
        const float* h_prev = hbuf + (t & 1) * (B_ * H_);
        float*       h2     = hbuf + ((t + 1) & 1) * (B_ * H_);

        // ---------------- P1: LSTM GEMM (all 512 blocks) ----------------
        {
            int vidx[16];
            #pragma unroll
            for (int b = 0; b < 16; ++b) vidx[b] = dec_in[b * T_ + t];
            float acc[16];
            #pragma unroll
            for (int b = 0; b < 16; ++b) acc[b] = 0.f;

            for (int g = 0; g < 18; ++g) {       // 72 k in groups of 4
                const int k = k0 + g * 4;
                const float* wp = Wk + (size_t)k * G4_ + col;
                const float w0 = wp[0];
                const float w1 = wp[G4_];
                const float w2 = wp[2 * G4_];
                const float w3 = wp[3 * G4_];
                if (k < E_) {
                    #pragma unroll
                    for (int b = 0; b < 16; ++b) {
                        const float4 xv = *(const float4*)(emb + (size_t)vidx[b] * E_ + k);
                        acc[b] = fmaf(xv.x, w0, acc[b]);
                        acc[b] = fmaf(xv.y, w1, acc[b]);
                        acc[b] = fmaf(xv.z, w2, acc[b]);
                        acc[b] = fmaf(xv.w, w3, acc[b]);
                    }
                } else {
                    const float* xb = (k < E_ + H_) ? (attnbuf + (k - E_))
                                                    : (h_prev + (k - E_ - H_));
                    #pragma unroll
                    for (int b = 0; b < 16; ++b) {
                        const float4 xv = *(const float4*)(xb + b * H_);
                        acc[b] = fmaf(xv.x, w0, acc[b]);
                        acc[b] = fmaf(xv.y, w1, acc[b]);
                        acc[b] = fmaf(xv.z, w2, acc[b]);
                        acc[b] = fmaf(xv.w, w3, acc[b]);
                    }
                }
            }
            #pragma unroll
            for (int b = 0; b < 16; ++b)
                zpart[(size_t)(ks * 16 + b) * G4_ + col] = acc[b];
        }
        gbar(cnt, ++e);

        // ---------------- P2: gates (tail 64 blocks) ----------------
        if (tail) {
            float z[4];
            #pragma unroll
            for (int g = 0; g < 4; ++g) {
                float s0 = bias[g * H_ + tb_hu], s1 = 0.f, s2 = 0.f, s3 = 0.f;
                #pragma unroll
                for (int kss = 0; kss < 32; kss += 4) {
                    s0 += zpart[(size_t)((kss + 0) * 16 + tb_b) * G4_ + g * H_ + tb_hu];
                    s1 += zpart[(size_t)((kss + 1) * 16 + tb_b) * G4_ + g * H_ + tb_hu];
                    s2 += zpart[(size_t)((kss + 2) * 16 + tb_b) * G4_ + g * H_ + tb_hu];
                    s3 += zpart[(size_t)((kss + 3) * 16 + tb_b) * G4_ + g * H_ + tb_hu];
                }
                z[g] = (s0 + s1) + (s2 + s3);
            }
            const float cn = creg * sigf(z[2] + 1.f) + sigf(z[0]) * tanhf(z[1]);
            const float hn = tanhf(cn) * sigf(z[3]);
            creg = cn;
            h2[tb_b * H_ + tb_hu] = hn;
        }
        gbar(cnt, ++e);

        // ---------------- P3: q partials (blocks 0..127) ----------------
        if (bid < 128) {
            const int qcc = bid & 3, qks = bid >> 2;     // 0..31
            const int qcol = qcc * 256 + tid;
            float qa[16];
            #pragma unroll
            for (int b = 0; b < 16; ++b) qa[b] = 0.f;
            #pragma unroll
            for (int g = 0; g < 8; ++g) {                // K=32 per split
                const int k = qks * 32 + g * 4;
                const float* wp = Wq + (size_t)k * H_ + qcol;
                const float w0 = wp[0], w1 = wp[H_], w2 = wp[2 * H_], w3 = wp[3 * H_];
                #pragma unroll
                for (int b = 0; b < 16; ++b) {
                    const float4 xv = *(const float4*)(h2 + b * H_ + k);
                    qa[b] = fmaf(xv.x, w0, qa[b]);
                    qa[b] = fmaf(xv.y, w1, qa[b]);
                    qa[b] = fmaf(xv.z, w2, qa[b]);
                    qa[b] = fmaf(xv.w, w3, qa[b]);
                }
            }
            #pragma unroll
            for (int b = 0; b < 16; ++b)
                qpart[(size_t)(qks * 16 + b) * H_ + qcol] = qa[b];
        }
        gbar(cnt, ++e);

        // ------- P4: per-(b,cc) q-reduce + scores + softmax + ctx -------
        if (bid < 64) {
            const int b = bid >> 2, ccc = bid & 3;
            {   // reduce 32 q partials for batch b into LDS (r0 order)
                const int c0 = tid * 4;
                float4 s0 = {0,0,0,0}, s1 = {0,0,0,0}, s2 = {0,0,0,0}, s3 = {0,0,0,0};
                #pragma unroll
                for (int kss = 0; kss < 32; kss += 4) {
                    const float4 p0 = *(const float4*)(qpart + (size_t)((kss + 0) * 16 + b) * H_ + c0);
                    const float4 p1 = *(const float4*)(qpart + (size_t)((kss + 1) * 16 + b) * H_ + c0);
                    const float4 p2 = *(const float4*)(qpart + (size_t)((kss + 2) * 16 + b) * H_ + c0);
                    const float4 p3 = *(const float4*)(qpart + (size_t)((kss + 3) * 16 + b) * H_ + c0);
                    s0.x += p0.x; s0.y += p0.y; s0.z += p0.z; s0.w += p0.w;
                    s1.x += p1.x; s1.y += p1.y; s1.z += p1.z; s1.w += p1.w;
                    s2.x += p2.x; s2.y += p2.y; s2.z += p2.z; s2.w += p2.w;
                    s3.x += p3.x; s3.y += p3.y; s3.z += p3.z; s3.w += p3.w;
                }
                qloc[c0 + 0] = (s0.x + s1.x) + (s2.x + s3.x);
                qloc[c0 + 1] = (s0.y + s1.y) + (s2.y + s3.y);
                qloc[c0 + 2] = (s0.z + s1.z) + (s2.z + s3.z);
                qloc[c0 + 3] = (s0.w + s1.w) + (s2.w + s3.w);
            }
            __syncthreads();
            const int wv = tid >> 6, lane = tid & 63;
            for (int tt = wv; tt < T_; tt += 4) {
                const float* kp = keys + ((size_t)b * T_ + tt) * H_;
                float s = 0.f;
                #pragma unroll
                for (int j = 0; j < 16; ++j) {
                    const int h = lane + j * 64;
                    s += tanhf(kp[h] + qloc[h]) * v_att[h];
                }
                #pragma unroll
                for (int off = 32; off; off >>= 1) s += __shfl_xor(s, off);
                if (lane == 0) sc[tt] = s;
            }
            __syncthreads();
            if (tid < 64) {
                const int len = enc_len[b];
                float s = (tid < len) ? sc[tid] : -1e9f;
                float m = s;
                #pragma unroll
                for (int off = 32; off; off >>= 1) m = fmaxf(m, __shfl_xor(m, off));
                const float ex = expf(s - m);
                float sum = ex;
                #pragma unroll
                for (int off = 32; off; off >>= 1) sum += __shfl_xor(sum, off);
                al[tid] = ex / sum;
            }
            __syncthreads();
            {
                const int colc = ccc * 256 + tid;
                const float* mp = memory + (size_t)b * T_ * H_ + colc;
                float a0 = 0.f, a1 = 0.f, a2 = 0.f, a3 = 0.f;
                #pragma unroll
                for (int t2 = 0; t2 < T_; t2 += 4) {
                    a0 = fmaf(al[t2 + 0], mp[(size_t)(t2 + 0) * H_], a0);
                    a1 = fmaf(al[t2 + 1], mp[(size_t)(t2 + 1) * H_], a1);
                    a2 = fmaf(al[t2 + 2], mp[(size_t)(t2 + 2) * H_], a2);
                    a3 = fmaf(al[t2 + 3], mp[(size_t)(t2 + 3) * H_], a3);
                }
                ctxbuf[b * H_ + colc] = (a0 + a1) + (a2 + a3);
            }
        }
        gbar(cnt, ++e);

        // ------- P5: attnout (in-block 16-way split-K) + finish -------
        if (bid < 64) {
            const int col5 = p5_hu0 + p5_ci;
            float aa[16];
            #pragma unroll
            for (int b = 0; b < 16; ++b) aa[b] = 0.f;
            for (int g = 0; g < 32; ++g) {       // K=128 per split
                const int k = p5_ks * 128 + g * 4;
                const float* wp = attnK + (size_t)k * H_ + col5;
                const float w0 = wp[0], w1 = wp[H_], w2 = wp[2 * H_], w3 = wp[3 * H_];
                const float* xb = (k < H_) ? (h2 + k) : (ctxbuf + (k - H_));
                #pragma unroll
                for (int b = 0; b < 16; ++b) {
                    const float4 xv = *(const float4*)(xb + b * H_);
                    aa[b] = fmaf(xv.x, w0, aa[b]);
                    aa[b] = fmaf(xv.y, w1, aa[b]);
                    aa[b] = fmaf(xv.z, w2, aa[b]);
                    aa[b] = fmaf(xv.w, w3, aa[b]);
                }
            }
            #pragma unroll
            for (int b = 0; b < 16; ++b) aps[p5_ks][p5_ci][b] = aa[b];
            __syncthreads();
            float s = 0.f;
            #pragma unroll
            for (int kss = 0; kss < 16; kss += 4)
                s += ((aps[kss + 0][p5_jg][p5_bg] + aps[kss + 1][p5_jg][p5_bg])
                   +  (aps[kss + 2][p5_jg][p5_bg] + aps[kss + 3][p5_jg][p5_bg]));
            attnbuf[p5_bg * H_ + p5_hu0 + p5_jg] = s;
            dec_out[((size_t)p5_bg * T_ + t) * H_ + p5_hu0 + p5_jg] =
                (t >= my_dl) ? 0.f : s;
            __syncthreads();                      // aps reused next step
        }
        if (t < T_ - 1) gbar(cnt, ++e);
    }
}

// ---------------------------------------------------------------------------
// Logits prep 1: split out_kernel fp32 [k][n] -> bf16 hi/lo TRANSPOSED [n][k].
// ---------------------------------------------------------------------------
__global__ __launch_bounds__(256) void bsplit_kernel(
    const float* __restrict__ Bw, ushort_t* __restrict__ Bh_t,
    ushort_t* __restrict__ Bl_t)
{
    __shared__ ushort_t Th[64][65];
    __shared__ ushort_t Tl[64][65];
    const int k0 = (blockIdx.x & 15) * 64;
    const int n0 = (blockIdx.x >> 4) * 64;
    const int tid = threadIdx.x;
    {
        const int nl = tid & 63, kb = tid >> 6;
        for (int i = 0; i < 16; ++i) {
            const int kl = kb + i * 4;
            const float f = Bw[(size_t)(k0 + kl) * V_ + n0 + nl];
            const ushort_t hi = f2b(f);
            Th[kl][nl] = hi;
            Tl[kl][nl] = f2b(f - b2f(hi));
        }
    }
    __syncthreads();
    {
        const int r = tid >> 2, c0 = (tid & 3) * 16;
        short8 vh0, vh1, vl0, vl1;
        #pragma unroll
        for (int j = 0; j < 8; ++j) {
            vh0[j] = (short)Th[c0 + j][r];
            vh1[j] = (short)Th[c0 + 8 + j][r];
            vl0[j] = (short)Tl[c0 + j][r];
            vl1[j] = (short)Tl[c0 + 8 + j][r];
        }
        ushort_t* ph = Bh_t + (size_t)(n0 + r) * 1024 + k0 + c0;
        ushort_t* pl = Bl_t + (size_t)(n0 + r) * 1024 + k0 + c0;
        *(short8*)ph = vh0;
        *(short8*)(ph + 8) = vh1;
        *(short8*)pl = vl0;
        *(short8*)(pl + 8) = vl1;
    }
}

// ---------------------------------------------------------------------------
// Logits prep 2: split dec_out fp32 [m][k] -> bf16 hi/lo [m][k]. Grid 512.
// ---------------------------------------------------------------------------
__global__ __launch_bounds__(256) void asplit_kernel(
    const float* __restrict__ A, ushort_t* __restrict__ Ah_g,
    ushort_t* __restrict__ Al_g)
{
    const size_t i0 = ((size_t)blockIdx.x * 256 + threadIdx.x) * 8;
    const float4 f0 = *(const float4*)(A + i0);
    const float4 f1 = *(const float4*)(A + i0 + 4);
    float f[8] = {f0.x, f0.y, f0.z, f0.w, f1.x, f1.y, f1.z, f1.w};
    short8 vh, vl;
    #pragma unroll
    for (int j = 0; j < 8; ++j) {
        const ushort_t hi = f2b(f[j]);
        vh[j] = (short)hi;
        vl[j] = (short)f2b(f[j] - b2f(hi));
    }
    *(short8*)(Ah_g + i0) = vh;
    *(short8*)(Al_g + i0) = vl;
}

// ---------------------------------------------------------------------------
// Logits from precomputed splits (direct global fragment loads + MFMA).
// ---------------------------------------------------------------------------
__global__ __launch_bounds__(256) void logits_pre_kernel(
    const ushort_t* __restrict__ Ah_g, const ushort_t* __restrict__ Al_g,
    const ushort_t* __restrict__ Bh_t, const ushort_t* __restrict__ Bl_t,
    float* __restrict__ out)
{
    const int tid = threadIdx.x;
    const int m0 = blockIdx.x * 128;
    const int n0 = blockIdx.y * 64;
    const int w = tid >> 6, lane = tid & 63;
    const int ml = lane & 15, quad = lane >> 4;

    float4v acc[2][4];
    #pragma unroll
    for (int ms = 0; ms < 2; ++ms)
        #pragma unroll
        for (int nn = 0; nn < 4; ++nn) acc[ms][nn] = (float4v){0.f, 0.f, 0.f, 0.f};

    const size_t arow0 = (size_t)(m0 + w * 32 + ml) * 1024;
    const size_t arow1 = (size_t)(m0 + w * 32 + 16 + ml) * 1024;

    for (int kb = 0; kb < 1024; kb += 32) {
        const int ko = kb + quad * 8;
        const short8 ah0 = *(const short8*)(Ah_g + arow0 + ko);
        const short8 al0 = *(const short8*)(Al_g + arow0 + ko);
        const short8 ah1 = *(const short8*)(Ah_g + arow1 + ko);
        const short8 al1 = *(const short8*)(Al_g + arow1 + ko);
        #pragma unroll
        for (int nn = 0; nn < 4; ++nn) {
            const size_t brow = (size_t)(n0 + nn * 16 + ml) * 1024 + ko;
            const short8 bfh = *(const short8*)(Bh_t + brow);
            const short8 bfl = *(const short8*)(Bl_t + brow);
            acc[0][nn] = __builtin_amdgcn_mfma_f32_16x16x32_bf16(ah0, bfh, acc[0][nn], 0, 0, 0);
            acc[0][nn] = __builtin_amdgcn_mfma_f32_16x16x32_bf16(ah0, bfl, acc[0][nn], 0, 0, 0);
            acc[0][nn] = __builtin_amdgcn_mfma_f32_16x16x32_bf16(al0, bfh, acc[0][nn], 0, 0, 0);
            acc[1][nn] = __builtin_amdgcn_mfma_f32_16x16x32_bf16(ah1, bfh, acc[1][nn], 0, 0, 0);
            acc[1][nn] = __builtin_amdgcn_mfma_f32_16x16x32_bf16(ah1, bfl, acc[1][nn], 0, 0, 0);
            acc[1][nn] = __builtin_amdgcn_mfma_f32_16x16x32_bf16(al1, bfh, acc[1][nn], 0, 0, 0);
        }
    }
    #pragma unroll
    for (int ms = 0; ms < 2; ++ms) {
        #pragma unroll
        for (int nn = 0; nn < 4; ++nn) {
            #pragma unroll
            for (int rg = 0; rg < 4; ++rg) {
                const int row = m0 + w * 32 + ms * 16 + quad * 4 + rg;
                const int colo = n0 + nn * 16 + ml;
                out[(size_t)row * V_ + colo] = acc[ms][nn][rg];
            }
        }
    }
}

// ---------------------------------------------------------------------------
// Fallback logits (in-kernel conversion, 64x64) — used if ws too small.
// ---------------------------------------------------------------------------
__global__ __launch_bounds__(256) void logits_kernel(
    const float* __restrict__ A, const float* __restrict__ Bw,
    float* __restrict__ out)
{
    __shared__ __align__(16) ushort_t Ah[64][44];
    __shared__ __align__(16) ushort_t Al[64][44];
    __shared__ __align__(16) ushort_t Bh[64][44];
    __shared__ __align__(16) ushort_t Bl[64][44];
    const int tid = threadIdx.x;
    const int m0 = blockIdx.x * 64;
    const int n0 = blockIdx.y * 64;
    const int wv = tid >> 6, lane = tid & 63;
    const int ml = lane & 15, quad = lane >> 4;

    float4v acc[4];
    #pragma unroll
    for (int nn = 0; nn < 4; ++nn) acc[nn] = (float4v){0.f, 0.f, 0.f, 0.f};

    for (int kb = 0; kb < 1024; kb += 32) {
        __syncthreads();
        {
            const int r = tid >> 2, c0 = (tid & 3) * 8;
            const float* ap = A + (size_t)(m0 + r) * 1024 + kb + c0;
            #pragma unroll
            for (int i = 0; i < 8; ++i) {
                const float f = ap[i];
                const ushort_t hi = f2b(f);
                Ah[r][c0 + i] = hi;
                Al[r][c0 + i] = f2b(f - b2f(hi));
            }
        }
        {
            const int cB = tid & 63, kq = tid >> 6;
            #pragma unroll
            for (int i = 0; i < 8; ++i) {
                const int k = kq * 8 + i;
                const float f = Bw[(size_t)(kb + k) * V_ + n0 + cB];
                const ushort_t hi = f2b(f);
                Bh[cB][k] = hi;
                Bl[cB][k] = f2b(f - b2f(hi));
            }
        }
        __syncthreads();
        const short8 afh = *(const short8*)&Ah[wv * 16 + ml][quad * 8];
        const short8 afl = *(const short8*)&Al[wv * 16 + ml][quad * 8];
        #pragma unroll
        for (int nn = 0; nn < 4; ++nn) {
            const short8 bfh = *(const short8*)&Bh[nn * 16 + ml][quad * 8];
            const short8 bfl = *(const short8*)&Bl[nn * 16 + ml][quad * 8];
            acc[nn] = __builtin_amdgcn_mfma_f32_16x16x32_bf16(afh, bfh, acc[nn], 0, 0, 0);
            acc[nn] = __builtin_amdgcn_mfma_f32_16x16x32_bf16(afh, bfl, acc[nn], 0, 0, 0);
            acc[nn] = __builtin_amdgcn_mfma_f32_16x16x32_bf16(afl, bfh, acc[nn], 0, 0, 0);
        }
    }
    #pragma unroll
    for (int nn = 0; nn < 4; ++nn) {
        #pragma unroll
        for (int rg = 0; rg < 4; ++rg) {
            const int row = m0 + wv * 16 + quad * 4 + rg;
            const int colo = n0 + nn * 16 + ml;
            out[(size_t)row * V_ + colo] = acc[nn][rg];
        }
    }
}

// ---------------------------------------------------------------------------
extern "C" void kernel_launch(void* const* d_in, const int* in_sizes, int n_in,
                              void* d_out, int out_size, void* d_ws, size_t ws_size,
                              hipStream_t stream) {
    (void)in_sizes; (void)n_in; (void)out_size;
    const int*   enc_in  = (const int*)d_in[0];
    const int*   dec_in  = (const int*)d_in[1];
    const int*   enc_len = (const int*)d_in[2];
    const int*   dec_len = (const int*)d_in[3];
    const float* emb     = (const float*)d_in[4];
    const float* encK    = (const float*)d_in[5];
    const float* encB    = (const float*)d_in[6];
    const float* decK    = (const float*)d_in[7];
    const float* decB    = (const float*)d_in[8];
    const float* Wm      = (const float*)d_in[9];
    const float* Wq      = (const float*)d_in[10];
    const float* v_att   = (const float*)d_in[11];
    const float* attnK   = (const float*)d_in[12];
    const float* outK    = (const float*)d_in[13];
    float* out = (float*)d_out;

    // Workspace layout (floats; base ~22.3 MB, optional bf16 split +135 MB).
    float* hbuf    = (float*)d_ws;                       // @0       (32768)
    float* cbuf    = hbuf + 32768;                       // @32768   (16384)
    float* attnbuf = cbuf + 16384;                       // @49152   (16384)
    float* ctxbuf  = attnbuf + 16384;                    // @65536   (16384)
    float* qpart   = ctxbuf + 16384;                     // @81920   (524288)
    int*   cnts    = (int*)(qpart + 524288);             // @606208  (1024 ints)
    float* zpart   = (float*)(cnts + 1024);              // @607232  (2097152)
    float* memory  = zpart + 2097152;                    // @2704384 (1048576)
    float* keys    = memory + 1048576;                   // @3752960 (1048576)
    float* dec_out = keys + 1048576;                     // @4801536 (1048576)
    float* base_end = dec_out + 1048576;                 // @5850112

    ushort_t* Ah_g = (ushort_t*)base_end;                // 2MB
    ushort_t* Al_g = Ah_g + (size_t)1024 * 1024;         // 2MB
    ushort_t* Bh_t = Al_g + (size_t)1024 * 1024;         // 65.5MB
    ushort_t* Bl_t = Bh_t + (size_t)V_ * 1024;           // 65.5MB
    const size_t need = 158666752ull;
    const bool use_pre = ws_size >= need;

    int* cnt_enc = cnts;                                 // lines 0..15, flag @+256
    int* cnt_dec = cnts + 512;

    // zero state (hbuf x2, cbuf, attnbuf, ctxbuf = 81920 floats) + counters
    init_kernel<<<320, 256, 0, stream>>>((float*)d_ws, cnts, 81920);

    if (use_pre)
        bsplit_kernel<<<16 * 500, 256, 0, stream>>>(outK, Bh_t, Bl_t);

    enc_persist_kernel<<<512, 256, 0, stream>>>(emb, enc_in, encK, encB, enc_len,
                                                hbuf, cbuf, memory, zpart, cnt_enc);
    keys_gemm_kernel<<<256, 256, 0, stream>>>(memory, Wm, keys);
    dec_persist_kernel<<<512, 256, 0, stream>>>(emb, dec_in, decK, decB, Wq, v_att,
                                                attnK, enc_len, dec_len, keys,
                                                memory, hbuf, cbuf, attnbuf,
                                                ctxbuf, qpart, zpart, dec_out,
                                                cnt_dec);

    if (use_pre) {
        asplit_kernel<<<512, 256, 0, stream>>>(dec_out, Ah_g, Al_g);
        logits_pre_kernel<<<dim3(8, 500), 256, 0, stream>>>(Ah_g, Al_g, Bh_t, Bl_t, out);
    } else {
        logits_kernel<<<dim3(16, 500), 256, 0, stream>>>(dec_out, outK, out);
    }
}